// Round 8
// baseline (2043.486 us; speedup 1.0000x reference)
//
#include <hip/hip_runtime.h>
#include <hip/hip_bf16.h>

typedef __bf16 bf16;
typedef __bf16 bf16x8 __attribute__((ext_vector_type(8)));
typedef float f32x4 __attribute__((ext_vector_type(4)));

// ---------------------------------------------------------------------------
// load 8 consecutive elements as bf16x8, converting from f32 if needed
// ---------------------------------------------------------------------------
template <typename T>
__device__ __forceinline__ bf16x8 load8(const T* p);

template <>
__device__ __forceinline__ bf16x8 load8<bf16>(const bf16* p) {
    return *(const bf16x8*)p;
}

template <>
__device__ __forceinline__ bf16x8 load8<float>(const float* p) {
    float4 a = *(const float4*)p;
    float4 b = *(const float4*)(p + 4);
    bf16x8 r;
    r[0] = (bf16)a.x; r[1] = (bf16)a.y; r[2] = (bf16)a.z; r[3] = (bf16)a.w;
    r[4] = (bf16)b.x; r[5] = (bf16)b.y; r[6] = (bf16)b.z; r[7] = (bf16)b.w;
    return r;
}

// ---------------------------------------------------------------------------
// C[M x N] = A[M x K] * B[N x K]^T
// TA/TB in {bf16,float} (converted to bf16 for MFMA), f32 accum, TC out.
// 128x128 tile, BK=32, 4 waves (2x2), each wave 4x4 of 16x16x32 MFMA.
// EPI==0: plain   EPI==1: softplus(acc + bias_f32[col])
// EPI==2: out = gmul_bf16[row,col] * silu(acc)
// ---------------------------------------------------------------------------
#define KP 40   // padded LDS row stride (bf16 elems); 80 B rows, 16B-aligned

template <int EPI, typename TA, typename TB, typename TC>
__global__ __launch_bounds__(256, 2) void gemm_bt(
    const TA* __restrict__ A, int lda,
    const TB* __restrict__ B, int ldb,
    TC* __restrict__ C, int ldc,
    int K, int Neff, const float* __restrict__ bias,
    const bf16* __restrict__ gmul)
{
    __shared__ bf16 As[128 * KP];
    __shared__ bf16 Bs[128 * KP];

    const int tid  = threadIdx.x;
    const int lane = tid & 63;
    const int wave = tid >> 6;
    const int quad = lane >> 4;
    const int l16  = lane & 15;
    const int wm   = (wave >> 1) << 6;
    const int wn   = (wave & 1) << 6;
    const int bm   = blockIdx.x << 7;
    const int bn   = blockIdx.y << 7;

    const int srow = tid >> 2;
    const int scol = (tid & 3) << 3;

    const TA* Ag0 = A + (size_t)(bm + srow) * lda + scol;
    const TA* Ag1 = Ag0 + (size_t)lda * 64;
    int br0 = bn + srow;      br0 = br0 < Neff ? br0 : Neff - 1;
    int br1 = bn + srow + 64; br1 = br1 < Neff ? br1 : Neff - 1;
    const TB* Bg0 = B + (size_t)br0 * ldb + scol;
    const TB* Bg1 = B + (size_t)br1 * ldb + scol;

    bf16* Asd = As + srow * KP + scol;
    bf16* Bsd = Bs + srow * KP + scol;

    f32x4 acc[4][4] = {};

    for (int k0 = 0; k0 < K; k0 += 32) {
        bf16x8 a0 = load8<TA>(Ag0 + k0);
        bf16x8 a1 = load8<TA>(Ag1 + k0);
        bf16x8 b0 = load8<TB>(Bg0 + k0);
        bf16x8 b1 = load8<TB>(Bg1 + k0);

        if (k0) __syncthreads();
        *(bf16x8*)(Asd)           = a0;
        *(bf16x8*)(Asd + 64 * KP) = a1;
        *(bf16x8*)(Bsd)           = b0;
        *(bf16x8*)(Bsd + 64 * KP) = b1;
        __syncthreads();

        bf16x8 af[4], bfr[4];
#pragma unroll
        for (int i = 0; i < 4; ++i) {
            af[i]  = *(const bf16x8*)(As + (wm + i * 16 + l16) * KP + quad * 8);
            bfr[i] = *(const bf16x8*)(Bs + (wn + i * 16 + l16) * KP + quad * 8);
        }
#pragma unroll
        for (int mi = 0; mi < 4; ++mi)
#pragma unroll
            for (int ni = 0; ni < 4; ++ni)
                acc[mi][ni] = __builtin_amdgcn_mfma_f32_16x16x32_bf16(
                    af[mi], bfr[ni], acc[mi][ni], 0, 0, 0);
    }

    // C/D layout: row = quad*4 + r, col = l16  (m89-verified)
#pragma unroll
    for (int mi = 0; mi < 4; ++mi) {
        const int row = bm + wm + mi * 16 + quad * 4;
#pragma unroll
        for (int ni = 0; ni < 4; ++ni) {
            const int col = bn + wn + ni * 16 + l16;
            if (col < Neff) {
                float bc = (EPI == 1) ? bias[col] : 0.f;
#pragma unroll
                for (int r = 0; r < 4; ++r) {
                    float v = acc[mi][ni][r];
                    if (EPI == 1) {
                        v += bc;
                        v = (v > 15.f) ? v : log1pf(__expf(v));
                    } else if (EPI == 2) {
                        float g = v / (1.f + __expf(-v));   // silu(z)
                        v = (float)gmul[(size_t)(row + r) * ldc + col] * g;
                    }
                    C[(size_t)(row + r) * ldc + col] = (TC)v;
                }
            }
        }
    }
}

// ---------------------------------------------------------------------------
// causal depthwise conv (k=4, left pad 3) + bias + SiLU: xh bf16 -> xc bf16
// conv_w/conv_b are f32. One block per (b,t): 256 threads x 8 channels.
// ---------------------------------------------------------------------------
__global__ __launch_bounds__(256) void conv_kernel(
    const bf16* __restrict__ xh, const float* __restrict__ cw,
    const float* __restrict__ cb, bf16* __restrict__ xc)
{
    const int bt = blockIdx.x;
    const int t  = bt & 2047;
    const int d  = threadIdx.x * 8;

    float4 wv[8];           // wv[i] = taps 0..3 of channel d+i
#pragma unroll
    for (int i = 0; i < 8; ++i)
        wv[i] = *(const float4*)(cw + (d + i) * 4);

    float4 cb0 = *(const float4*)(cb + d);
    float4 cb1 = *(const float4*)(cb + d + 4);
    float acc[8] = { cb0.x, cb0.y, cb0.z, cb0.w, cb1.x, cb1.y, cb1.z, cb1.w };

#pragma unroll
    for (int j = 0; j < 4; ++j) {
        int ts = t - 3 + j;
        if (ts >= 0) {
            bf16x8 v = *(const bf16x8*)(xh + (size_t)(bt - (3 - j)) * 2048 + d);
#pragma unroll
            for (int i = 0; i < 8; ++i) {
                float w = (j == 0) ? wv[i].x : (j == 1) ? wv[i].y
                        : (j == 2) ? wv[i].z : wv[i].w;
                acc[i] += w * (float)v[i];
            }
        }
    }

    bf16x8 o;
#pragma unroll
    for (int i = 0; i < 8; ++i) {
        float s = acc[i];
        o[i] = (bf16)(s / (1.f + __expf(-s)));
    }
    *(bf16x8*)(xc + (size_t)bt * 2048 + d) = o;
}

// ---------------------------------------------------------------------------
// selective scan: thread = (b, n, d); lane&15 = n (shuffle group).
// 8-deep double-buffered prefetch: 32 independent bf16 loads in flight per
// thread (ring holds RAW bf16 -- cvt at consumption so waitcnt lands there).
// Writes UNGATED ry = sum_n C*h + D*x IN PLACE over xc (same-wave lockstep:
// the xc[t] load is consumed -- forcing waitcnt -- before the t-store).
// ---------------------------------------------------------------------------
__global__ __launch_bounds__(256) void scan_kernel(
    const bf16* __restrict__ delta, const bf16* __restrict__ dbc,
    const float* __restrict__ A_raw, const float* __restrict__ Dvec,
    const bf16* xc, bf16* ry)
{
    const int tid = threadIdx.x;
    const int n   = tid & 15;
    const int dl  = tid >> 4;
    const int b   = blockIdx.y;
    const int d   = (blockIdx.x << 4) + dl;

    const float A  = -expf(A_raw[n * 2048 + d]);
    const float Dd = Dvec[d];

    const size_t xbase = ((size_t)b * 2048) * 2048 + d;      // + t*2048
    const size_t bbase = ((size_t)b * 2048) * 96 + 64 + n;   // B; C at +16

    bf16 xv[2][8], dv[2][8], Bv[2][8], Cv[2][8];

#pragma unroll
    for (int j = 0; j < 8; ++j) {
        xv[0][j] = xc   [xbase + (size_t)j * 2048];
        dv[0][j] = delta[xbase + (size_t)j * 2048];
        Bv[0][j] = dbc  [bbase + (size_t)j * 96];
        Cv[0][j] = dbc  [bbase + (size_t)j * 96 + 16];
    }

    float h = 0.f;
    for (int g = 0; g < 256; ++g) {
        const int cur = g & 1, nxt = cur ^ 1;
        if (g < 255) {
            const size_t xo = xbase + (size_t)(g + 1) * 8 * 2048;
            const size_t bo = bbase + (size_t)(g + 1) * 8 * 96;
#pragma unroll
            for (int j = 0; j < 8; ++j) {
                xv[nxt][j] = xc   [xo + (size_t)j * 2048];
                dv[nxt][j] = delta[xo + (size_t)j * 2048];
                Bv[nxt][j] = dbc  [bo + (size_t)j * 96];
                Cv[nxt][j] = dbc  [bo + (size_t)j * 96 + 16];
            }
        }
#pragma unroll
        for (int j = 0; j < 8; ++j) {
            const float xt = (float)xv[cur][j];
            const float dt = (float)dv[cur][j];
            const float e  = __expf(dt * A);
            h = e * h + (dt * (float)Bv[cur][j]) * xt;
            float c = (float)Cv[cur][j] * h;
            c += __shfl_xor(c, 1, 16);
            c += __shfl_xor(c, 2, 16);
            c += __shfl_xor(c, 4, 16);
            c += __shfl_xor(c, 8, 16);
            if (n == 0)
                ry[xbase + (size_t)(g * 8 + j) * 2048] = (bf16)(c + Dd * xt);
        }
    }
}

// ---------------------------------------------------------------------------
// launch.  Inputs: f32. Output: f32.  Workspace (>=64 MiB proven):
//   buf0 [0,   32Mi): xh -> delta -> y      (bf16)
//   buf1 [32Mi,64Mi): xc -> ry (in place)   (bf16)
//   dbc (1.5 MiB bf16) in d_out head; dead before gemm7 overwrites d_out.
// z never materialized: gating fused into the z-GEMM epilogue (EPI=2).
// ---------------------------------------------------------------------------
extern "C" void kernel_launch(void* const* d_in, const int* in_sizes, int n_in,
                              void* d_out, int out_size, void* d_ws, size_t ws_size,
                              hipStream_t stream)
{
    const float* x      = (const float*)d_in[0];
    const float* W_in   = (const float*)d_in[1];
    const float* conv_w = (const float*)d_in[2];
    const float* conv_b = (const float*)d_in[3];
    const float* W_x    = (const float*)d_in[4];
    const float* W_dt   = (const float*)d_in[5];
    const float* b_dt   = (const float*)d_in[6];
    const float* A_raw  = (const float*)d_in[7];
    const float* Dvec   = (const float*)d_in[8];
    const float* W_out  = (const float*)d_in[9];
    float* out = (float*)d_out;

    char* ws = (char*)d_ws;
    bf16* buf0 = (bf16*)(ws + 0);          // xh -> delta -> y
    bf16* buf1 = (bf16*)(ws + 33554432);   // xc -> ry
    bf16* dbc  = (bf16*)d_out;             // 1,572,864 B, dead before gemm7

    // 1) xh = x @ W_in[:2048]^T          M=8192 N=2048 K=1024
    gemm_bt<0, float, float, bf16><<<dim3(64, 16), 256, 0, stream>>>(
        x, 1024, W_in, 1024, buf0, 2048, 1024, 2048, nullptr, nullptr);
    // 2) xc = silu(causal_conv(xh) + cb)
    conv_kernel<<<dim3(8192), 256, 0, stream>>>(buf0, conv_w, conv_b, buf1);
    // 3) dbc = xc @ W_x^T                M=8192 N=96 K=2048
    gemm_bt<0, bf16, float, bf16><<<dim3(64, 1), 256, 0, stream>>>(
        buf1, 2048, W_x, 2048, dbc, 96, 2048, 96, nullptr, nullptr);
    // 4) delta = softplus(dt @ W_dt^T + b_dt)   (lda=96, K=64)
    gemm_bt<1, bf16, float, bf16><<<dim3(64, 16), 256, 0, stream>>>(
        dbc, 96, W_dt, 64, buf0, 2048, 64, 2048, b_dt, nullptr);
    // 5) scan -> ry (ungated), in place over xc
    scan_kernel<<<dim3(128, 4), 256, 0, stream>>>(
        buf0, dbc, A_raw, Dvec, buf1, buf1);
    // 6) y = ry * silu(x @ W_in[2048:]^T)   (fused z-GEMM + gate)
    gemm_bt<2, float, float, bf16><<<dim3(64, 16), 256, 0, stream>>>(
        x, 1024, W_in + (size_t)2048 * 1024, 1024, buf0, 2048, 1024, 2048,
        nullptr, buf1);
    // 7) out = y @ W_out^T  (f32 store)  M=8192 N=1024 K=2048
    gemm_bt<0, bf16, float, float><<<dim3(64, 8), 256, 0, stream>>>(
        buf0, 2048, W_out, 2048, out, 1024, 2048, 1024, nullptr, nullptr);
}

// Round 9
// 1095.197 us; speedup vs baseline: 1.8659x; 1.8659x over previous
//
#include <hip/hip_runtime.h>
#include <hip/hip_bf16.h>

typedef __bf16 bf16;
typedef __bf16 bf16x8 __attribute__((ext_vector_type(8)));
typedef float f32x4 __attribute__((ext_vector_type(4)));

// ---------------------------------------------------------------------------
// load 8 consecutive elements as bf16x8, converting from f32 if needed
// ---------------------------------------------------------------------------
template <typename T>
__device__ __forceinline__ bf16x8 load8(const T* p);

template <>
__device__ __forceinline__ bf16x8 load8<bf16>(const bf16* p) {
    return *(const bf16x8*)p;
}

template <>
__device__ __forceinline__ bf16x8 load8<float>(const float* p) {
    float4 a = *(const float4*)p;
    float4 b = *(const float4*)(p + 4);
    bf16x8 r;
    r[0] = (bf16)a.x; r[1] = (bf16)a.y; r[2] = (bf16)a.z; r[3] = (bf16)a.w;
    r[4] = (bf16)b.x; r[5] = (bf16)b.y; r[6] = (bf16)b.z; r[7] = (bf16)b.w;
    return r;
}

// ---------------------------------------------------------------------------
// C[M x N] = A[M x K] * B[N x K]^T
// TA/TB in {bf16,float} (converted to bf16 for MFMA), f32 accum, TC out.
// 128x128 tile, BK=32, 4 waves (2x2), each wave 4x4 of 16x16x32 MFMA.
// EPI==0: plain   EPI==1: softplus(acc + bias_f32[col])
// EPI==2: out = gmul_bf16[row,col] * silu(acc)
// ---------------------------------------------------------------------------
#define KP 40   // padded LDS row stride (bf16 elems); 80 B rows, 16B-aligned

template <int EPI, typename TA, typename TB, typename TC>
__global__ __launch_bounds__(256, 2) void gemm_bt(
    const TA* __restrict__ A, int lda,
    const TB* __restrict__ B, int ldb,
    TC* __restrict__ C, int ldc,
    int K, int Neff, const float* __restrict__ bias,
    const bf16* __restrict__ gmul)
{
    __shared__ bf16 As[128 * KP];
    __shared__ bf16 Bs[128 * KP];

    const int tid  = threadIdx.x;
    const int lane = tid & 63;
    const int wave = tid >> 6;
    const int quad = lane >> 4;
    const int l16  = lane & 15;
    const int wm   = (wave >> 1) << 6;
    const int wn   = (wave & 1) << 6;
    const int bm   = blockIdx.x << 7;
    const int bn   = blockIdx.y << 7;

    const int srow = tid >> 2;
    const int scol = (tid & 3) << 3;

    const TA* Ag0 = A + (size_t)(bm + srow) * lda + scol;
    const TA* Ag1 = Ag0 + (size_t)lda * 64;
    int br0 = bn + srow;      br0 = br0 < Neff ? br0 : Neff - 1;
    int br1 = bn + srow + 64; br1 = br1 < Neff ? br1 : Neff - 1;
    const TB* Bg0 = B + (size_t)br0 * ldb + scol;
    const TB* Bg1 = B + (size_t)br1 * ldb + scol;

    bf16* Asd = As + srow * KP + scol;
    bf16* Bsd = Bs + srow * KP + scol;

    f32x4 acc[4][4] = {};

    for (int k0 = 0; k0 < K; k0 += 32) {
        bf16x8 a0 = load8<TA>(Ag0 + k0);
        bf16x8 a1 = load8<TA>(Ag1 + k0);
        bf16x8 b0 = load8<TB>(Bg0 + k0);
        bf16x8 b1 = load8<TB>(Bg1 + k0);

        if (k0) __syncthreads();
        *(bf16x8*)(Asd)           = a0;
        *(bf16x8*)(Asd + 64 * KP) = a1;
        *(bf16x8*)(Bsd)           = b0;
        *(bf16x8*)(Bsd + 64 * KP) = b1;
        __syncthreads();

        bf16x8 af[4], bfr[4];
#pragma unroll
        for (int i = 0; i < 4; ++i) {
            af[i]  = *(const bf16x8*)(As + (wm + i * 16 + l16) * KP + quad * 8);
            bfr[i] = *(const bf16x8*)(Bs + (wn + i * 16 + l16) * KP + quad * 8);
        }
#pragma unroll
        for (int mi = 0; mi < 4; ++mi)
#pragma unroll
            for (int ni = 0; ni < 4; ++ni)
                acc[mi][ni] = __builtin_amdgcn_mfma_f32_16x16x32_bf16(
                    af[mi], bfr[ni], acc[mi][ni], 0, 0, 0);
    }

    // C/D layout: row = quad*4 + r, col = l16  (m89-verified)
#pragma unroll
    for (int mi = 0; mi < 4; ++mi) {
        const int row = bm + wm + mi * 16 + quad * 4;
#pragma unroll
        for (int ni = 0; ni < 4; ++ni) {
            const int col = bn + wn + ni * 16 + l16;
            if (col < Neff) {
                float bc = (EPI == 1) ? bias[col] : 0.f;
#pragma unroll
                for (int r = 0; r < 4; ++r) {
                    float v = acc[mi][ni][r];
                    if (EPI == 1) {
                        v += bc;
                        v = (v > 15.f) ? v : log1pf(__expf(v));
                    } else if (EPI == 2) {
                        float g = v / (1.f + __expf(-v));   // silu(z)
                        v = (float)gmul[(size_t)(row + r) * ldc + col] * g;
                    }
                    C[(size_t)(row + r) * ldc + col] = (TC)v;
                }
            }
        }
    }
}

// ---------------------------------------------------------------------------
// causal depthwise conv (k=4, left pad 3) + bias + SiLU: xh bf16 -> xc bf16
// ---------------------------------------------------------------------------
__global__ __launch_bounds__(256) void conv_kernel(
    const bf16* __restrict__ xh, const float* __restrict__ cw,
    const float* __restrict__ cb, bf16* __restrict__ xc)
{
    const int bt = blockIdx.x;
    const int t  = bt & 2047;
    const int d  = threadIdx.x * 8;

    float4 wv[8];           // wv[i] = taps 0..3 of channel d+i
#pragma unroll
    for (int i = 0; i < 8; ++i)
        wv[i] = *(const float4*)(cw + (d + i) * 4);

    float4 cb0 = *(const float4*)(cb + d);
    float4 cb1 = *(const float4*)(cb + d + 4);
    float acc[8] = { cb0.x, cb0.y, cb0.z, cb0.w, cb1.x, cb1.y, cb1.z, cb1.w };

#pragma unroll
    for (int j = 0; j < 4; ++j) {
        int ts = t - 3 + j;
        if (ts >= 0) {
            bf16x8 v = *(const bf16x8*)(xh + (size_t)(bt - (3 - j)) * 2048 + d);
#pragma unroll
            for (int i = 0; i < 8; ++i) {
                float w = (j == 0) ? wv[i].x : (j == 1) ? wv[i].y
                        : (j == 2) ? wv[i].z : wv[i].w;
                acc[i] += w * (float)v[i];
            }
        }
    }

    bf16x8 o;
#pragma unroll
    for (int i = 0; i < 8; ++i) {
        float s = acc[i];
        o[i] = (bf16)(s / (1.f + __expf(-s)));
    }
    *(bf16x8*)(xc + (size_t)bt * 2048 + d) = o;
}

// ---------------------------------------------------------------------------
// selective scan: thread = (b, n, d); lane&15 = n (shuffle group).
// Depth-8 prefetch, STATIC double banks (A/B named arrays, unroll-by-2 group
// loop) so every index is compile-time -> full VGPR promotion (r8's dynamic
// [cur] index sent the banks to scratch: VGPR 60, VALUBusy 68%, 2.3x slower).
// Writes UNGATED ry = sum_n C*h + D*x IN PLACE over xc (prefetches target
// strictly future t; writes strictly past t; vmcnt FIFO keeps banks apart).
// ---------------------------------------------------------------------------
__global__ __launch_bounds__(256) void scan_kernel(
    const bf16* __restrict__ delta, const bf16* __restrict__ dbc,
    const float* __restrict__ A_raw, const float* __restrict__ Dvec,
    const bf16* xc, bf16* ry)
{
    const int tid = threadIdx.x;
    const int n   = tid & 15;
    const int dl  = tid >> 4;
    const int b   = blockIdx.y;
    const int d   = (blockIdx.x << 4) + dl;

    const float A  = -expf(A_raw[n * 2048 + d]);
    const float Dd = Dvec[d];

    const size_t xbase = ((size_t)b * 2048) * 2048 + d;      // + t*2048
    const size_t bbase = ((size_t)b * 2048) * 96 + 64 + n;   // B; C at +16

    bf16 xA[8], dA[8], BA[8], CA[8];
    bf16 xB[8], dB[8], BB[8], CB[8];
    float h = 0.f;

#define PF(bank, grp) do {                                                    \
    const size_t xo_ = xbase + (size_t)(grp) * 8 * 2048;                      \
    const size_t bo_ = bbase + (size_t)(grp) * 8 * 96;                        \
    _Pragma("unroll")                                                         \
    for (int j = 0; j < 8; ++j) {                                             \
        x##bank[j] = xc   [xo_ + (size_t)j * 2048];                           \
        d##bank[j] = delta[xo_ + (size_t)j * 2048];                           \
        B##bank[j] = dbc  [bo_ + (size_t)j * 96];                             \
        C##bank[j] = dbc  [bo_ + (size_t)j * 96 + 16];                        \
    } } while (0)

#define CONSUME(bank, grp) do {                                               \
    _Pragma("unroll")                                                         \
    for (int j = 0; j < 8; ++j) {                                             \
        const float xt = (float)x##bank[j];                                   \
        const float dt = (float)d##bank[j];                                   \
        const float e  = __expf(dt * A);                                      \
        h = e * h + (dt * (float)B##bank[j]) * xt;                            \
        float c = (float)C##bank[j] * h;                                      \
        c += __shfl_xor(c, 1, 16);                                            \
        c += __shfl_xor(c, 2, 16);                                            \
        c += __shfl_xor(c, 4, 16);                                            \
        c += __shfl_xor(c, 8, 16);                                            \
        if (n == 0)                                                           \
            ry[xbase + (size_t)((grp) * 8 + j) * 2048] = (bf16)(c + Dd * xt); \
    } } while (0)

    PF(A, 0);
    for (int g = 0; g < 256; g += 2) {
        PF(B, g + 1);            // g+1 <= 255 always
        CONSUME(A, g);
        if (g + 2 < 256) PF(A, g + 2);
        CONSUME(B, g + 1);
    }
#undef PF
#undef CONSUME
}

// ---------------------------------------------------------------------------
// launch.  Inputs: f32. Output: f32.  Workspace (>=64 MiB proven):
//   buf0 [0,   32Mi): xh -> delta -> y      (bf16)
//   buf1 [32Mi,64Mi): xc -> ry (in place)   (bf16)
//   dbc (1.5 MiB bf16) in d_out head; dead before gemm7 overwrites d_out.
// z never materialized: gating fused into the z-GEMM epilogue (EPI=2).
// ---------------------------------------------------------------------------
extern "C" void kernel_launch(void* const* d_in, const int* in_sizes, int n_in,
                              void* d_out, int out_size, void* d_ws, size_t ws_size,
                              hipStream_t stream)
{
    const float* x      = (const float*)d_in[0];
    const float* W_in   = (const float*)d_in[1];
    const float* conv_w = (const float*)d_in[2];
    const float* conv_b = (const float*)d_in[3];
    const float* W_x    = (const float*)d_in[4];
    const float* W_dt   = (const float*)d_in[5];
    const float* b_dt   = (const float*)d_in[6];
    const float* A_raw  = (const float*)d_in[7];
    const float* Dvec   = (const float*)d_in[8];
    const float* W_out  = (const float*)d_in[9];
    float* out = (float*)d_out;

    char* ws = (char*)d_ws;
    bf16* buf0 = (bf16*)(ws + 0);          // xh -> delta -> y
    bf16* buf1 = (bf16*)(ws + 33554432);   // xc -> ry
    bf16* dbc  = (bf16*)d_out;             // 1,572,864 B, dead before gemm7

    // 1) xh = x @ W_in[:2048]^T          M=8192 N=2048 K=1024
    gemm_bt<0, float, float, bf16><<<dim3(64, 16), 256, 0, stream>>>(
        x, 1024, W_in, 1024, buf0, 2048, 1024, 2048, nullptr, nullptr);
    // 2) xc = silu(causal_conv(xh) + cb)
    conv_kernel<<<dim3(8192), 256, 0, stream>>>(buf0, conv_w, conv_b, buf1);
    // 3) dbc = xc @ W_x^T                M=8192 N=96 K=2048
    gemm_bt<0, bf16, float, bf16><<<dim3(64, 1), 256, 0, stream>>>(
        buf1, 2048, W_x, 2048, dbc, 96, 2048, 96, nullptr, nullptr);
    // 4) delta = softplus(dt @ W_dt^T + b_dt)   (lda=96, K=64)
    gemm_bt<1, bf16, float, bf16><<<dim3(64, 16), 256, 0, stream>>>(
        dbc, 96, W_dt, 64, buf0, 2048, 64, 2048, b_dt, nullptr);
    // 5) scan -> ry (ungated), in place over xc
    scan_kernel<<<dim3(128, 4), 256, 0, stream>>>(
        buf0, dbc, A_raw, Dvec, buf1, buf1);
    // 6) y = ry * silu(x @ W_in[2048:]^T)   (fused z-GEMM + gate)
    gemm_bt<2, float, float, bf16><<<dim3(64, 16), 256, 0, stream>>>(
        x, 1024, W_in + (size_t)2048 * 1024, 1024, buf0, 2048, 1024, 2048,
        nullptr, buf1);
    // 7) out = y @ W_out^T  (f32 store)  M=8192 N=1024 K=2048
    gemm_bt<0, bf16, float, float><<<dim3(64, 8), 256, 0, stream>>>(
        buf0, 2048, W_out, 2048, out, 1024, 2048, 1024, nullptr, nullptr);
}

// Round 10
// 828.390 us; speedup vs baseline: 2.4668x; 1.3221x over previous
//
#include <hip/hip_runtime.h>
#include <hip/hip_bf16.h>

typedef __bf16 bf16;
typedef __bf16 bf16x8 __attribute__((ext_vector_type(8)));
typedef float f32x4 __attribute__((ext_vector_type(4)));

// ---------------------------------------------------------------------------
// load 8 consecutive elements as bf16x8, converting from f32 if needed
// ---------------------------------------------------------------------------
template <typename T>
__device__ __forceinline__ bf16x8 load8(const T* p);

template <>
__device__ __forceinline__ bf16x8 load8<bf16>(const bf16* p) {
    return *(const bf16x8*)p;
}

template <>
__device__ __forceinline__ bf16x8 load8<float>(const float* p) {
    float4 a = *(const float4*)p;
    float4 b = *(const float4*)(p + 4);
    bf16x8 r;
    r[0] = (bf16)a.x; r[1] = (bf16)a.y; r[2] = (bf16)a.z; r[3] = (bf16)a.w;
    r[4] = (bf16)b.x; r[5] = (bf16)b.y; r[6] = (bf16)b.z; r[7] = (bf16)b.w;
    return r;
}

// ---------------------------------------------------------------------------
// C[M x N] = A[M x K] * B[N x K]^T
// TA/TB in {bf16,float} (converted to bf16 for MFMA), f32 accum, TC out.
// 128x128 tile, BK=32, 4 waves (2x2), each wave 4x4 of 16x16x32 MFMA.
// EPI==0: plain   EPI==1: softplus(acc + bias_f32[col])
// EPI==2: out = gmul_bf16[row,col] * silu(acc)
// ---------------------------------------------------------------------------
#define KP 40   // padded LDS row stride (bf16 elems); 80 B rows, 16B-aligned

template <int EPI, typename TA, typename TB, typename TC>
__global__ __launch_bounds__(256, 2) void gemm_bt(
    const TA* __restrict__ A, int lda,
    const TB* __restrict__ B, int ldb,
    TC* __restrict__ C, int ldc,
    int K, int Neff, const float* __restrict__ bias,
    const bf16* __restrict__ gmul)
{
    __shared__ bf16 As[128 * KP];
    __shared__ bf16 Bs[128 * KP];

    const int tid  = threadIdx.x;
    const int lane = tid & 63;
    const int wave = tid >> 6;
    const int quad = lane >> 4;
    const int l16  = lane & 15;
    const int wm   = (wave >> 1) << 6;
    const int wn   = (wave & 1) << 6;
    const int bm   = blockIdx.x << 7;
    const int bn   = blockIdx.y << 7;

    const int srow = tid >> 2;
    const int scol = (tid & 3) << 3;

    const TA* Ag0 = A + (size_t)(bm + srow) * lda + scol;
    const TA* Ag1 = Ag0 + (size_t)lda * 64;
    int br0 = bn + srow;      br0 = br0 < Neff ? br0 : Neff - 1;
    int br1 = bn + srow + 64; br1 = br1 < Neff ? br1 : Neff - 1;
    const TB* Bg0 = B + (size_t)br0 * ldb + scol;
    const TB* Bg1 = B + (size_t)br1 * ldb + scol;

    bf16* Asd = As + srow * KP + scol;
    bf16* Bsd = Bs + srow * KP + scol;

    f32x4 acc[4][4] = {};

    for (int k0 = 0; k0 < K; k0 += 32) {
        bf16x8 a0 = load8<TA>(Ag0 + k0);
        bf16x8 a1 = load8<TA>(Ag1 + k0);
        bf16x8 b0 = load8<TB>(Bg0 + k0);
        bf16x8 b1 = load8<TB>(Bg1 + k0);

        if (k0) __syncthreads();
        *(bf16x8*)(Asd)           = a0;
        *(bf16x8*)(Asd + 64 * KP) = a1;
        *(bf16x8*)(Bsd)           = b0;
        *(bf16x8*)(Bsd + 64 * KP) = b1;
        __syncthreads();

        bf16x8 af[4], bfr[4];
#pragma unroll
        for (int i = 0; i < 4; ++i) {
            af[i]  = *(const bf16x8*)(As + (wm + i * 16 + l16) * KP + quad * 8);
            bfr[i] = *(const bf16x8*)(Bs + (wn + i * 16 + l16) * KP + quad * 8);
        }
#pragma unroll
        for (int mi = 0; mi < 4; ++mi)
#pragma unroll
            for (int ni = 0; ni < 4; ++ni)
                acc[mi][ni] = __builtin_amdgcn_mfma_f32_16x16x32_bf16(
                    af[mi], bfr[ni], acc[mi][ni], 0, 0, 0);
    }

    // C/D layout: row = quad*4 + r, col = l16  (m89-verified)
#pragma unroll
    for (int mi = 0; mi < 4; ++mi) {
        const int row = bm + wm + mi * 16 + quad * 4;
#pragma unroll
        for (int ni = 0; ni < 4; ++ni) {
            const int col = bn + wn + ni * 16 + l16;
            if (col < Neff) {
                float bc = (EPI == 1) ? bias[col] : 0.f;
#pragma unroll
                for (int r = 0; r < 4; ++r) {
                    float v = acc[mi][ni][r];
                    if (EPI == 1) {
                        v += bc;
                        v = (v > 15.f) ? v : log1pf(__expf(v));
                    } else if (EPI == 2) {
                        float g = v / (1.f + __expf(-v));   // silu(z)
                        v = (float)gmul[(size_t)(row + r) * ldc + col] * g;
                    }
                    C[(size_t)(row + r) * ldc + col] = (TC)v;
                }
            }
        }
    }
}

// ---------------------------------------------------------------------------
// causal depthwise conv (k=4, left pad 3) + bias + SiLU: xh bf16 -> xc bf16
// ---------------------------------------------------------------------------
__global__ __launch_bounds__(256) void conv_kernel(
    const bf16* __restrict__ xh, const float* __restrict__ cw,
    const float* __restrict__ cb, bf16* __restrict__ xc)
{
    const int bt = blockIdx.x;
    const int t  = bt & 2047;
    const int d  = threadIdx.x * 8;

    float4 wv[8];           // wv[i] = taps 0..3 of channel d+i
#pragma unroll
    for (int i = 0; i < 8; ++i)
        wv[i] = *(const float4*)(cw + (d + i) * 4);

    float4 cb0 = *(const float4*)(cb + d);
    float4 cb1 = *(const float4*)(cb + d + 4);
    float acc[8] = { cb0.x, cb0.y, cb0.z, cb0.w, cb1.x, cb1.y, cb1.z, cb1.w };

#pragma unroll
    for (int j = 0; j < 4; ++j) {
        int ts = t - 3 + j;
        if (ts >= 0) {
            bf16x8 v = *(const bf16x8*)(xh + (size_t)(bt - (3 - j)) * 2048 + d);
#pragma unroll
            for (int i = 0; i < 8; ++i) {
                float w = (j == 0) ? wv[i].x : (j == 1) ? wv[i].y
                        : (j == 2) ? wv[i].z : wv[i].w;
                acc[i] += w * (float)v[i];
            }
        }
    }

    bf16x8 o;
#pragma unroll
    for (int i = 0; i < 8; ++i) {
        float s = acc[i];
        o[i] = (bf16)(s / (1.f + __expf(-s)));
    }
    *(bf16x8*)(xc + (size_t)bt * 2048 + d) = o;
}

// ---------------------------------------------------------------------------
// Chunk-parallel selective scan (NC=32 chunks x TC=64 t).
// Thread = (b, n, d); lane&15 = n.  h_t = exp(dt*A)h + dt*B*x.
//
// Pass 1: per chunk from h=0: H_c = local h end, A_c = exp(A * sum(dt)).
// Pass 2: H~_c = H_c + A_c * H~_{c-1}   (sequential over 32, in-place).
// Pass 3: rescan chunk from H~_{c-1}; y = sum_n C*h + D*x -> ry (over xc).
// Parallelism x32 -> ~8 blocks/CU co-resident: latency hidden by TLP.
// ---------------------------------------------------------------------------
__global__ __launch_bounds__(256) void scan_p1(
    const bf16* __restrict__ delta, const bf16* __restrict__ dbc,
    const float* __restrict__ A_raw, const bf16* __restrict__ xc,
    float* __restrict__ Hbuf, bf16* __restrict__ Abuf)
{
    const int tid = threadIdx.x;
    const int n   = tid & 15;
    const int dl  = tid >> 4;
    const int b   = blockIdx.y;
    const int c   = blockIdx.z;
    const int d   = (blockIdx.x << 4) + dl;

    const float A = -expf(A_raw[n * 2048 + d]);

    const size_t xbase = ((size_t)b * 2048 + (size_t)c * 64) * 2048 + d;
    const size_t bbase = ((size_t)b * 2048 + (size_t)c * 64) * 96 + 64 + n;

    bf16 x0[8], d0[8], B0[8];
    bf16 x1[8], d1[8], B1[8];
    float h = 0.f, sdt = 0.f;

#define PF1(XX, DD, BB, grp) do {                                   \
    const size_t xo_ = xbase + (size_t)(grp) * 8 * 2048;            \
    const size_t bo_ = bbase + (size_t)(grp) * 8 * 96;              \
    _Pragma("unroll")                                               \
    for (int j = 0; j < 8; ++j) {                                   \
        XX[j] = xc[xo_ + (size_t)j * 2048];                         \
        DD[j] = delta[xo_ + (size_t)j * 2048];                      \
        BB[j] = dbc[bo_ + (size_t)j * 96];                          \
    } } while (0)

#define CO1(XX, DD, BB) do {                                        \
    _Pragma("unroll")                                               \
    for (int j = 0; j < 8; ++j) {                                   \
        const float xt = (float)XX[j];                              \
        const float dt = (float)DD[j];                              \
        const float e  = __expf(dt * A);                            \
        h = e * h + (dt * (float)BB[j]) * xt;                       \
        sdt += dt;                                                  \
    } } while (0)

    PF1(x0, d0, B0, 0);
    PF1(x1, d1, B1, 1);
    CO1(x0, d0, B0);  PF1(x0, d0, B0, 2);
    CO1(x1, d1, B1);  PF1(x1, d1, B1, 3);
    CO1(x0, d0, B0);  PF1(x0, d0, B0, 4);
    CO1(x1, d1, B1);  PF1(x1, d1, B1, 5);
    CO1(x0, d0, B0);  PF1(x0, d0, B0, 6);
    CO1(x1, d1, B1);  PF1(x1, d1, B1, 7);
    CO1(x0, d0, B0);
    CO1(x1, d1, B1);
#undef PF1
#undef CO1

    const size_t hidx = (((size_t)b * 32 + c) * 16 + n) * 2048 + d;
    Hbuf[hidx] = h;
    Abuf[hidx] = (bf16)__expf(A * sdt);
}

__global__ __launch_bounds__(256) void scan_p2(
    float* __restrict__ Hbuf, const bf16* __restrict__ Abuf)
{
    const int id  = blockIdx.x * 256 + threadIdx.x;   // 131072 = b*32768+n*2048+d
    const int b   = id >> 15;
    const int rem = id & 32767;
    const size_t base = (size_t)b * 32 * 32768 + rem;  // chunk stride 32768

    float Hv[32]; bf16 Av[32];
#pragma unroll
    for (int c = 0; c < 32; ++c) {
        Hv[c] = Hbuf[base + (size_t)c * 32768];
        Av[c] = Abuf[base + (size_t)c * 32768];
    }
    float ht = Hv[0];                      // H~_0 = H_0 (already stored)
#pragma unroll
    for (int c = 1; c < 32; ++c) {
        ht = Hv[c] + (float)Av[c] * ht;
        Hbuf[base + (size_t)c * 32768] = ht;
    }
}

__global__ __launch_bounds__(256) void scan_p3(
    const bf16* __restrict__ delta, const bf16* __restrict__ dbc,
    const float* __restrict__ A_raw, const float* __restrict__ Dvec,
    const float* __restrict__ Hbuf, const bf16* xc, bf16* ry)
{
    const int tid = threadIdx.x;
    const int n   = tid & 15;
    const int dl  = tid >> 4;
    const int b   = blockIdx.y;
    const int c   = blockIdx.z;
    const int d   = (blockIdx.x << 4) + dl;

    const float A  = -expf(A_raw[n * 2048 + d]);
    const float Dd = Dvec[d];

    float h = 0.f;
    if (c > 0)
        h = Hbuf[(((size_t)b * 32 + (c - 1)) * 16 + n) * 2048 + d];

    const size_t xbase = ((size_t)b * 2048 + (size_t)c * 64) * 2048 + d;
    const size_t bbase = ((size_t)b * 2048 + (size_t)c * 64) * 96 + 64 + n;

    bf16 x0[8], d0[8], B0[8], C0[8];
    bf16 x1[8], d1[8], B1[8], C1[8];

#define PF3(XX, DD, BB, CC, grp) do {                               \
    const size_t xo_ = xbase + (size_t)(grp) * 8 * 2048;            \
    const size_t bo_ = bbase + (size_t)(grp) * 8 * 96;              \
    _Pragma("unroll")                                               \
    for (int j = 0; j < 8; ++j) {                                   \
        XX[j] = xc[xo_ + (size_t)j * 2048];                         \
        DD[j] = delta[xo_ + (size_t)j * 2048];                      \
        BB[j] = dbc[bo_ + (size_t)j * 96];                          \
        CC[j] = dbc[bo_ + (size_t)j * 96 + 16];                     \
    } } while (0)

#define CO3(XX, DD, BB, CC, grp) do {                               \
    _Pragma("unroll")                                               \
    for (int j = 0; j < 8; ++j) {                                   \
        const float xt = (float)XX[j];                              \
        const float dt = (float)DD[j];                              \
        const float e  = __expf(dt * A);                            \
        h = e * h + (dt * (float)BB[j]) * xt;                       \
        float cv = (float)CC[j] * h;                                \
        cv += __shfl_xor(cv, 1, 16);                                \
        cv += __shfl_xor(cv, 2, 16);                                \
        cv += __shfl_xor(cv, 4, 16);                                \
        cv += __shfl_xor(cv, 8, 16);                                \
        if (n == 0)                                                 \
            ry[xbase + (size_t)((grp) * 8 + j) * 2048] =            \
                (bf16)(cv + Dd * xt);                               \
    } } while (0)

    PF3(x0, d0, B0, C0, 0);
    PF3(x1, d1, B1, C1, 1);
    CO3(x0, d0, B0, C0, 0);  PF3(x0, d0, B0, C0, 2);
    CO3(x1, d1, B1, C1, 1);  PF3(x1, d1, B1, C1, 3);
    CO3(x0, d0, B0, C0, 2);  PF3(x0, d0, B0, C0, 4);
    CO3(x1, d1, B1, C1, 3);  PF3(x1, d1, B1, C1, 5);
    CO3(x0, d0, B0, C0, 4);  PF3(x0, d0, B0, C0, 6);
    CO3(x1, d1, B1, C1, 5);  PF3(x1, d1, B1, C1, 7);
    CO3(x0, d0, B0, C0, 6);
    CO3(x1, d1, B1, C1, 7);
#undef PF3
#undef CO3
}

// ---------------------------------------------------------------------------
// launch.  Inputs: f32. Output: f32.  Workspace (>=64 MiB proven):
//   buf0 [0,   32Mi): xh -> delta -> y      (bf16)
//   buf1 [32Mi,64Mi): xc -> ry (in place)   (bf16)
// d_out (32 MiB, dead until gemm7):
//   dbc bf16 @0 (1.5 MiB) | Hbuf f32 @2Mi (16 MiB) | Abuf bf16 @20Mi (8 MiB)
// z never materialized: gating fused into the z-GEMM epilogue (EPI=2).
// ---------------------------------------------------------------------------
extern "C" void kernel_launch(void* const* d_in, const int* in_sizes, int n_in,
                              void* d_out, int out_size, void* d_ws, size_t ws_size,
                              hipStream_t stream)
{
    const float* x      = (const float*)d_in[0];
    const float* W_in   = (const float*)d_in[1];
    const float* conv_w = (const float*)d_in[2];
    const float* conv_b = (const float*)d_in[3];
    const float* W_x    = (const float*)d_in[4];
    const float* W_dt   = (const float*)d_in[5];
    const float* b_dt   = (const float*)d_in[6];
    const float* A_raw  = (const float*)d_in[7];
    const float* Dvec   = (const float*)d_in[8];
    const float* W_out  = (const float*)d_in[9];
    float* out = (float*)d_out;

    char* ws = (char*)d_ws;
    bf16*  buf0 = (bf16*)(ws + 0);          // xh -> delta -> y
    bf16*  buf1 = (bf16*)(ws + 33554432);   // xc -> ry
    bf16*  dbc  = (bf16*)d_out;
    float* Hbuf = (float*)((char*)d_out + 2097152);
    bf16*  Abuf = (bf16*)((char*)d_out + 20971520);

    // 1) xh = x @ W_in[:2048]^T          M=8192 N=2048 K=1024
    gemm_bt<0, float, float, bf16><<<dim3(64, 16), 256, 0, stream>>>(
        x, 1024, W_in, 1024, buf0, 2048, 1024, 2048, nullptr, nullptr);
    // 2) xc = silu(causal_conv(xh) + cb)
    conv_kernel<<<dim3(8192), 256, 0, stream>>>(buf0, conv_w, conv_b, buf1);
    // 3) dbc = xc @ W_x^T                M=8192 N=96 K=2048
    gemm_bt<0, bf16, float, bf16><<<dim3(64, 1), 256, 0, stream>>>(
        buf1, 2048, W_x, 2048, dbc, 96, 2048, 96, nullptr, nullptr);
    // 4) delta = softplus(dt @ W_dt^T + b_dt)   (lda=96, K=64)
    gemm_bt<1, bf16, float, bf16><<<dim3(64, 16), 256, 0, stream>>>(
        dbc, 96, W_dt, 64, buf0, 2048, 64, 2048, b_dt, nullptr);
    // 5) chunk-parallel scan -> ry (ungated), in place over xc
    scan_p1<<<dim3(128, 4, 32), 256, 0, stream>>>(
        buf0, dbc, A_raw, buf1, Hbuf, Abuf);
    scan_p2<<<dim3(512), 256, 0, stream>>>(Hbuf, Abuf);
    scan_p3<<<dim3(128, 4, 32), 256, 0, stream>>>(
        buf0, dbc, A_raw, Dvec, Hbuf, buf1, buf1);
    // 6) y = ry * silu(x @ W_in[2048:]^T)   (fused z-GEMM + gate)
    gemm_bt<2, float, float, bf16><<<dim3(64, 16), 256, 0, stream>>>(
        x, 1024, W_in + (size_t)2048 * 1024, 1024, buf0, 2048, 1024, 2048,
        nullptr, buf1);
    // 7) out = y @ W_out^T  (f32 store)  M=8192 N=1024 K=2048
    gemm_bt<0, bf16, float, float><<<dim3(64, 8), 256, 0, stream>>>(
        buf0, 2048, W_out, 2048, out, 1024, 2048, 1024, nullptr, nullptr);
}